// Round 8
// baseline (389.133 us; speedup 1.0000x reference)
//
#include <hip/hip_runtime.h>
#include <hip/hip_bf16.h>
#include <math.h>

#define NN 100000
#define EE 1600000
#define FIN 256
#define HID 64
#define NC 40
#define NB 196        // destination buckets of 512 nodes (196*512 = 100352)
#define BCAP 10240    // staging capacity per bucket (mean 8192, +22 sigma)
#define CHUNK 2048    // edges per bucket_kernel block
#define NBKB ((EE + CHUNK - 1) / CHUNK)   // 782

typedef unsigned long long ull;
typedef __attribute__((ext_vector_type(2))) unsigned long long ullx2;
typedef __attribute__((ext_vector_type(8))) short short8;
typedef __attribute__((ext_vector_type(4))) float f32x4;

__device__ __forceinline__ unsigned short f2bf_rne(float f) {
    unsigned u = __float_as_uint(f);
    u += 0x7FFFu + ((u >> 16) & 1u);
    return (unsigned short)(u >> 16);
}
__device__ __forceinline__ float bf2f(unsigned short b) {
    return __uint_as_float((unsigned)b << 16);
}

// accumulate one edge: q = (w<<32)|src ; tbl rows are 32 dwords (64 bf16)
__device__ __forceinline__ void edge_acc(ull q, const unsigned* __restrict__ tbl,
                                         int fl, float& a0, float& a1) {
    unsigned src = (unsigned)q & 0x1FFFFu;
    unsigned u = tbl[(src << 5) | fl];
    float w = __int_as_float((int)(q >> 32));
    a0 += w * __uint_as_float(u << 16);
    a1 += w * __uint_as_float(u & 0xFFFF0000u);
}

// ---- stage edges into destination buckets; LDS-reorder by bucket for coalesced writes ----
__global__ __launch_bounds__(256) void bucket_kernel(const int* __restrict__ row,
                                                     const int* __restrict__ col,
                                                     const float* __restrict__ w,
                                                     int* __restrict__ bucket_cnt,
                                                     int2* __restrict__ staging) {
    __shared__ int2 spay[CHUNK];            // 16 KB  original-order payload
    __shared__ int2 sorted[CHUNK];          // 16 KB  bucket-ordered payload
    __shared__ unsigned char sb[CHUNK];     // 2 KB   bucket id per original slot
    __shared__ unsigned char sbk[CHUNK];    // 2 KB   bucket id per sorted slot
    __shared__ int lcnt[NB], lofs[NB], lstart[NB];
    __shared__ int sscan[256];
    const int tid = threadIdx.x;
    const int e0 = blockIdx.x * CHUNK;
    const int nE = min(CHUNK, EE - e0);
    for (int i = tid; i < nE; i += 256) {
        int e = e0 + i;
        int c = col[e];
        sb[i] = (unsigned char)(c >> 9);
        spay[i] = make_int2(((c & 511) << 17) | row[e], __float_as_int(w[e]));
    }
    for (int i = tid; i < NB; i += 256) lcnt[i] = 0;
    __syncthreads();
    for (int i = tid; i < nE; i += 256) atomicAdd(&lcnt[sb[i]], 1);
    __syncthreads();
    // exclusive scan of lcnt over NB (<=256)
    int v = (tid < NB) ? lcnt[tid] : 0;
    sscan[tid] = v;
    __syncthreads();
    for (int off = 1; off < 256; off <<= 1) {
        int u = (tid >= off) ? sscan[tid - off] : 0;
        __syncthreads();
        sscan[tid] += u;
        __syncthreads();
    }
    if (tid < NB) {
        lofs[tid] = sscan[tid] - v;                       // local exclusive prefix
        lstart[tid] = v ? atomicAdd(&bucket_cnt[tid], v) : 0;  // global base for this block's run
        lcnt[tid] = 0;
    }
    __syncthreads();
    // reorder into bucket-contiguous LDS
    for (int i = tid; i < nE; i += 256) {
        int b = sb[i];
        int p = lofs[b] + atomicAdd(&lcnt[b], 1);
        sorted[p] = spay[i];
        sbk[p] = (unsigned char)b;
    }
    __syncthreads();
    // write out: consecutive threads -> consecutive slots of the same bucket
    for (int p = tid; p < nE; p += 256) {
        int b = sbk[p];
        int slot = lstart[b] + (p - lofs[b]);
        if (slot < BCAP) staging[(size_t)b * BCAP + slot] = sorted[p];
    }
}

// ---- build pass A: per-dest count+degree; within-bucket scan of PADDED degrees ----
// basev <- within-bucket padded offset (fixed up in pass B); endv <- actual count
__global__ __launch_bounds__(512) void build_count_kernel(const int2* __restrict__ staging,
                                                          const int* __restrict__ bucket_cnt,
                                                          int* __restrict__ basev,
                                                          int* __restrict__ endv,
                                                          float* __restrict__ dis,
                                                          int* __restrict__ ptot) {
    __shared__ int dcnt[512];
    __shared__ float dsum[512];
    __shared__ int sscan[512];
    const int t = threadIdx.x;
    const int b = blockIdx.x;
    const int nE = min(bucket_cnt[b], BCAP);
    const int2* st = staging + (size_t)b * BCAP;
    dcnt[t] = 0; dsum[t] = 0.f;
    __syncthreads();
    for (int i = t; i < nE; i += 512) {
        int2 p = st[i];
        int d = p.x >> 17;
        atomicAdd(&dcnt[d], 1);
        atomicAdd(&dsum[d], __int_as_float(p.y));
    }
    __syncthreads();
    int c = dcnt[t];
    int pdeg = (c + 7) & ~7;       // pad each node's range to multiple of 8
    sscan[t] = pdeg;
    __syncthreads();
    for (int off = 1; off < 512; off <<= 1) {
        int u = (t >= off) ? sscan[t - off] : 0;
        __syncthreads();
        sscan[t] += u;
        __syncthreads();
    }
    int gd = b * 512 + t;
    if (gd < NN) {
        basev[gd] = sscan[t] - pdeg;   // within-bucket padded exclusive prefix
        endv[gd] = c;                  // actual count (temporarily)
        dis[gd] = rsqrtf(dsum[t] + 1.0f);   // self-loop weight 1
    }
    if (t == 511) ptot[b] = sscan[511];    // bucket padded total
}

// ---- block 0: exclusive scan of bucket padded totals; blocks 1..4: W1 -> B^T bf16 hi/lo ----
__global__ __launch_bounds__(256) void bscan_w1cvt_kernel(const int* __restrict__ ptot,
                                                          int* __restrict__ bucket_base,
                                                          const float* __restrict__ W1,
                                                          unsigned short* __restrict__ w1hi,
                                                          unsigned short* __restrict__ w1lo) {
    if (blockIdx.x == 0) {
        __shared__ int sd[256];
        int t = threadIdx.x;
        int v = (t < NB) ? ptot[t] : 0;
        sd[t] = v;
        __syncthreads();
        for (int off = 1; off < 256; off <<= 1) {
            int u = (t >= off) ? sd[t - off] : 0;
            __syncthreads();
            sd[t] += u;
            __syncthreads();
        }
        if (t < NB) bucket_base[t] = sd[t] - v;
    } else {
        int b = blockIdx.x - 1;          // 0..3
        for (int i = threadIdx.x; i < 4096; i += 256) {
            int e = b * 4096 + i;        // e = c*256 + k  (B^T layout)
            int c = e >> 8, k = e & 255;
            float v = W1[(size_t)k * HID + c];
            unsigned short h = f2bf_rne(v);
            w1hi[e] = h;
            w1lo[e] = f2bf_rne(v - bf2f(h));
        }
    }
}

// ---- build pass B: fix up global bases, place normalized edges, zero-fill pads ----
__global__ __launch_bounds__(512) void build_place_kernel(const int2* __restrict__ staging,
                                                          const int* __restrict__ bucket_cnt,
                                                          const int* __restrict__ bucket_base,
                                                          int* __restrict__ basev,
                                                          int* __restrict__ endv,
                                                          const float* __restrict__ dis,
                                                          int2* __restrict__ eme) {
    __shared__ int dcur[512];
    __shared__ float sdis[512];
    const int t = threadIdx.x;
    const int b = blockIdx.x;
    const int nE = min(bucket_cnt[b], BCAP);
    const int2* st = staging + (size_t)b * BCAP;
    const int gd = b * 512 + t;
    int gb = 0, c = 0, pdeg = 0;
    if (gd < NN) {
        gb = bucket_base[b] + basev[gd];
        c = endv[gd];
        pdeg = (c + 7) & ~7;
        basev[gd] = gb;
        endv[gd] = gb + c;
        sdis[t] = dis[gd];
    } else {
        sdis[t] = 0.f;
    }
    dcur[t] = gb;
    __syncthreads();
    for (int i = t; i < nE; i += 512) {
        int2 p = st[i];
        int d = p.x >> 17;
        int src = p.x & 0x1FFFF;
        int pos = atomicAdd(&dcur[d], 1);
        float wn = __int_as_float(p.y) * dis[src] * sdis[d];
        eme[pos] = make_int2(src, __float_as_int(wn));
    }
    // zero-weight pads: src=0 (valid row) x 0 weight
    for (int i = c; i < pdeg; i++) eme[gb + i] = make_int2(0, 0);
}

// ---- GEMM1 (MFMA, split-bf16 f32 emulation): xw[N,64](bf16) = x[N,256] @ W1[256,64] ----
// 16 rows/wave (6252 waves -> grid allows ~6/SIMD), VGPR cap 128 via launch_bounds,
// explicit double-buffered B prefetch keeps 8 L2 loads in flight under the MFMAs.
__global__ __launch_bounds__(256, 4) void gemm1_mfma_kernel(const float* __restrict__ x,
                                                            const unsigned short* __restrict__ w1hi,
                                                            const unsigned short* __restrict__ w1lo,
                                                            __hip_bfloat16* __restrict__ xw) {
    const int tid = threadIdx.x;
    const int wid = tid >> 6;
    const int l   = tid & 63;
    const int r   = l & 15;        // A row within 16-tile / B col within 16-tile
    const int kg  = l >> 4;        // k-group 0..3 (8 contiguous k each)
    const int rb0 = blockIdx.x * 64 + wid * 16;   // wave's 16 rows

    f32x4 acc[4];
#pragma unroll
    for (int j = 0; j < 4; j++) acc[j] = (f32x4){0.f, 0.f, 0.f, 0.f};

    int row0 = rb0 + r;
    int row0c = row0 < NN ? row0 : NN - 1;   // clamp loads; stores are guarded
    const float* ap = x + (size_t)row0c * FIN + kg * 8;
    const unsigned short* bp = w1hi + (size_t)r * FIN + kg * 8;  // col r base (hi)
    const unsigned short* lp = w1lo + (size_t)r * FIN + kg * 8;  // col r base (lo)

    // double-buffered B fragments: [stage][ct]
    short8 bhi[2][4], blo[2][4];
#pragma unroll
    for (int ct = 0; ct < 4; ct++) {
        bhi[0][ct] = *(const short8*)(bp + (size_t)ct * 16 * FIN);
        blo[0][ct] = *(const short8*)(lp + (size_t)ct * 16 * FIN);
    }
#pragma unroll
    for (int ks = 0; ks < 8; ks++) {
        const int cur = ks & 1, nxt = cur ^ 1;
        if (ks < 7) {
#pragma unroll
            for (int ct = 0; ct < 4; ct++) {
                bhi[nxt][ct] = *(const short8*)(bp + (size_t)ct * 16 * FIN + (ks + 1) * 32);
                blo[nxt][ct] = *(const short8*)(lp + (size_t)ct * 16 * FIN + (ks + 1) * 32);
            }
        }
        // A: 8 contiguous f32 for this row-tile
        float4 afa = *(const float4*)(ap + ks * 32);
        float4 afb = *(const float4*)(ap + ks * 32 + 4);
        float av[8] = {afa.x, afa.y, afa.z, afa.w, afb.x, afb.y, afb.z, afb.w};
        short8 ahi, alo;
#pragma unroll
        for (int j = 0; j < 8; j++) {
            unsigned short h = f2bf_rne(av[j]);
            ahi[j] = (short)h;
            alo[j] = (short)f2bf_rne(av[j] - bf2f(h));
        }
#pragma unroll
        for (int ct = 0; ct < 4; ct++) {
            acc[ct] = __builtin_amdgcn_mfma_f32_16x16x32_bf16(ahi, bhi[cur][ct], acc[ct], 0, 0, 0);
            acc[ct] = __builtin_amdgcn_mfma_f32_16x16x32_bf16(ahi, blo[cur][ct], acc[ct], 0, 0, 0);
            acc[ct] = __builtin_amdgcn_mfma_f32_16x16x32_bf16(alo, bhi[cur][ct], acc[ct], 0, 0, 0);
        }
    }
    // C/D layout: col = lane&15, row = (lane>>4)*4 + reg
#pragma unroll
    for (int i = 0; i < 4; i++) {
        int grow = rb0 + kg * 4 + i;
        if (grow < NN) {
            unsigned short* dst = (unsigned short*)xw + (size_t)grow * HID + r;
#pragma unroll
            for (int ct = 0; ct < 4; ct++)
                dst[ct * 16] = f2bf_rne(acc[ct][i]);
        }
    }
}

// ---- gather1: padded ranges -> zero predication, contiguous 16B loads ----
// Half h of the wave takes the h-th contiguous 8-edge sub-block of each 16-batch.
__global__ __launch_bounds__(256) void gather1_kernel(const int* __restrict__ basev,
                                                      const int* __restrict__ endv,
                                                      const ull* __restrict__ eme,
                                                      const unsigned* __restrict__ xw32,
                                                      const float* __restrict__ dis,
                                                      const float* __restrict__ b,
                                                      float* __restrict__ h) {
    int n = blockIdx.x * 4 + (threadIdx.x >> 6);
    if (n >= NN) return;
    int lane = threadIdx.x & 63;
    int half = lane >> 5;
    int fl = lane & 31;            // feature-pair index (features 2fl, 2fl+1)
    int s = basev[n], t = endv[n];
    int pdeg = (t - s + 7) & ~7;   // padded range length (pads are zero-weight)
    float acc0 = 0.f, acc1 = 0.f;
    int nb16 = pdeg >> 4;
    for (int bi = 0; bi < nb16; bi++) {
        const ull* pp = eme + s + bi * 16 + 8 * half;   // 16B-aligned by construction
        ullx2 qa = *(const ullx2*)(pp);
        ullx2 qb = *(const ullx2*)(pp + 2);
        ullx2 qc = *(const ullx2*)(pp + 4);
        ullx2 qd = *(const ullx2*)(pp + 6);
        edge_acc(qa[0], xw32, fl, acc0, acc1);
        edge_acc(qa[1], xw32, fl, acc0, acc1);
        edge_acc(qb[0], xw32, fl, acc0, acc1);
        edge_acc(qb[1], xw32, fl, acc0, acc1);
        edge_acc(qc[0], xw32, fl, acc0, acc1);
        edge_acc(qc[1], xw32, fl, acc0, acc1);
        edge_acc(qd[0], xw32, fl, acc0, acc1);
        edge_acc(qd[1], xw32, fl, acc0, acc1);
    }
    if (pdeg & 8) {                 // one 8-edge batch, 4 edges per half
        const ull* pp = eme + s + nb16 * 16 + 4 * half;
        ullx2 qa = *(const ullx2*)(pp);
        ullx2 qb = *(const ullx2*)(pp + 2);
        edge_acc(qa[0], xw32, fl, acc0, acc1);
        edge_acc(qa[1], xw32, fl, acc0, acc1);
        edge_acc(qb[0], xw32, fl, acc0, acc1);
        edge_acc(qb[1], xw32, fl, acc0, acc1);
    }
    acc0 += __shfl_xor(acc0, 32);
    acc1 += __shfl_xor(acc1, 32);
    float d = dis[n];
    unsigned un = xw32[((unsigned)n << 5) | fl];
    float2 bv = *(const float2*)(b + 2 * fl);
    float v0 = acc0 + d * d * __uint_as_float(un << 16) + bv.x;
    float v1 = acc1 + d * d * __uint_as_float(un & 0xFFFF0000u) + bv.y;
    if (lane < 32) {
        *(float2*)(h + (size_t)n * HID + 2 * fl) = make_float2(fmaxf(v0, 0.f), fmaxf(v1, 0.f));
    }
}

// ---- GEMM2: hw2[N,64-padded](bf16) = h[N,64] @ W2[64,40]; rows padded to one 128B line ----
__global__ __launch_bounds__(256) void gemm2_kernel(const float* __restrict__ h,
                                                    const float* __restrict__ W,
                                                    __hip_bfloat16* __restrict__ hw) {
    __shared__ float hs[64][65];
    __shared__ float Ws[HID * NC];
    const int tid = threadIdx.x;
    const int base = blockIdx.x * 64;
    for (int v = tid; v < 1024; v += 256) {
        int r = v >> 4, q = v & 15;
        int gr = base + r;
        float4 hv = make_float4(0.f, 0.f, 0.f, 0.f);
        if (gr < NN) hv = *(const float4*)(h + (size_t)gr * HID + q * 4);
        hs[r][q * 4 + 0] = hv.x; hs[r][q * 4 + 1] = hv.y;
        hs[r][q * 4 + 2] = hv.z; hs[r][q * 4 + 3] = hv.w;
    }
    for (int v = tid; v < HID * NC; v += 256) Ws[v] = W[v];
    __syncthreads();
    const int tx = tid & 7;
    const int ty = tid >> 3;
    float acc[2][5] = {};
#pragma unroll 8
    for (int k = 0; k < HID; k++) {
        float h0 = hs[ty * 2 + 0][k];
        float h1 = hs[ty * 2 + 1][k];
        const float* wr = &Ws[k * NC + tx * 5];
        float w0 = wr[0], w1 = wr[1], w2 = wr[2], w3 = wr[3], w4 = wr[4];
        acc[0][0] += h0 * w0; acc[0][1] += h0 * w1; acc[0][2] += h0 * w2;
        acc[0][3] += h0 * w3; acc[0][4] += h0 * w4;
        acc[1][0] += h1 * w0; acc[1][1] += h1 * w1; acc[1][2] += h1 * w2;
        acc[1][3] += h1 * w3; acc[1][4] += h1 * w4;
    }
#pragma unroll
    for (int i = 0; i < 2; i++) {
        int gr = base + ty * 2 + i;
        if (gr < NN) {
#pragma unroll
            for (int c = 0; c < 5; c++)
                hw[(size_t)gr * 64 + tx * 5 + c] = __float2bfloat16(acc[i][c]);
        }
    }
}

// ---- gather2 + final: padded ranges, zero predication; log_softmax fused ----
__global__ __launch_bounds__(256) void gather2_kernel(const int* __restrict__ basev,
                                                      const int* __restrict__ endv,
                                                      const ull* __restrict__ eme,
                                                      const unsigned* __restrict__ hw32,
                                                      const float* __restrict__ dis,
                                                      const float* __restrict__ b,
                                                      float* __restrict__ out) {
    int n = blockIdx.x * 4 + (threadIdx.x >> 6);
    if (n >= NN) return;
    int lane = threadIdx.x & 63;
    int half = lane >> 5;
    int fl = lane & 31;
    bool act = fl < 20;            // classes 2fl, 2fl+1 < 40
    int s = basev[n], t = endv[n];
    int pdeg = (t - s + 7) & ~7;
    float acc0 = 0.f, acc1 = 0.f;
    int nb16 = pdeg >> 4;
    for (int bi = 0; bi < nb16; bi++) {
        const ull* pp = eme + s + bi * 16 + 8 * half;
        ullx2 qa = *(const ullx2*)(pp);
        ullx2 qb = *(const ullx2*)(pp + 2);
        ullx2 qc = *(const ullx2*)(pp + 4);
        ullx2 qd = *(const ullx2*)(pp + 6);
        edge_acc(qa[0], hw32, fl, acc0, acc1);
        edge_acc(qa[1], hw32, fl, acc0, acc1);
        edge_acc(qb[0], hw32, fl, acc0, acc1);
        edge_acc(qb[1], hw32, fl, acc0, acc1);
        edge_acc(qc[0], hw32, fl, acc0, acc1);
        edge_acc(qc[1], hw32, fl, acc0, acc1);
        edge_acc(qd[0], hw32, fl, acc0, acc1);
        edge_acc(qd[1], hw32, fl, acc0, acc1);
    }
    if (pdeg & 8) {
        const ull* pp = eme + s + nb16 * 16 + 4 * half;
        ullx2 qa = *(const ullx2*)(pp);
        ullx2 qb = *(const ullx2*)(pp + 2);
        edge_acc(qa[0], hw32, fl, acc0, acc1);
        edge_acc(qa[1], hw32, fl, acc0, acc1);
        edge_acc(qb[0], hw32, fl, acc0, acc1);
        edge_acc(qb[1], hw32, fl, acc0, acc1);
    }
    acc0 += __shfl_xor(acc0, 32);
    acc1 += __shfl_xor(acc1, 32);
    float v0 = 0.f, v1 = 0.f, m = -INFINITY;
    if (act) {
        float d = dis[n];
        unsigned un = hw32[((unsigned)n << 5) | fl];
        float2 bv = *(const float2*)(b + 2 * fl);
        v0 = acc0 + d * d * __uint_as_float(un << 16) + bv.x;
        v1 = acc1 + d * d * __uint_as_float(un & 0xFFFF0000u) + bv.y;
        m = fmaxf(v0, v1);
    }
#pragma unroll
    for (int off = 16; off; off >>= 1) m = fmaxf(m, __shfl_xor(m, off));
    float e0 = act ? expf(v0 - m) : 0.f;
    float e1 = act ? expf(v1 - m) : 0.f;
    float sum = e0 + e1;
#pragma unroll
    for (int off = 16; off; off >>= 1) sum += __shfl_xor(sum, off);
    float lse = m + logf(sum);
    if (act && lane < 32) {
        size_t idx = (size_t)n * NC + 2 * fl;
        *(float2*)(out + idx) = make_float2(v0, v1);
        *(float2*)(out + (size_t)NN * NC + idx) = make_float2(v0 - lse, v1 - lse);
    }
}

extern "C" void kernel_launch(void* const* d_in, const int* in_sizes, int n_in,
                              void* d_out, int out_size, void* d_ws, size_t ws_size,
                              hipStream_t stream) {
    const float* x    = (const float*)d_in[0];
    const int*   eidx = (const int*)d_in[1];
    const float* ew   = (const float*)d_in[2];
    const float* W1   = (const float*)d_in[3];
    const float* b1   = (const float*)d_in[4];
    const float* W2   = (const float*)d_in[5];
    const float* b2   = (const float*)d_in[6];
    float* out = (float*)d_out;

    const int* row = eidx;
    const int* col = eidx + EE;

    char* ws = (char*)d_ws;
    int*   bucket_cnt  = (int*)ws;               ws += 256 * 4;
    int*   bucket_base = (int*)ws;               ws += 256 * 4;
    int*   ptot        = (int*)ws;               ws += 256 * 4;
    float* dis    = (float*)ws;                  ws += NN * 4;
    int*   basev  = (int*)ws;                    ws += NN * 4;
    int*   endv   = (int*)ws;                    ws += NN * 4;
    int2*  eme    = (int2*)ws;                   ws += ((size_t)EE + 8 * NN) * 8;  // padded
    __hip_bfloat16* xw = (__hip_bfloat16*)ws;    ws += (size_t)NN * HID * 2;
    // staging (16.06 MB) and h (25.6 MB) are never live simultaneously: union them
    char* unionp = ws;                           ws += (size_t)NN * HID * 4;
    int2*  staging = (int2*)unionp;              // NB*BCAP*8 = 16.06 MB <= 25.6 MB
    float* h       = (float*)unionp;
    __hip_bfloat16* hw2 = (__hip_bfloat16*)ws;   ws += (size_t)NN * 64 * 2;  // stride-64 padded
    unsigned short* w1hi = (unsigned short*)ws;  ws += (size_t)HID * FIN * 2; // B^T bf16 hi
    unsigned short* w1lo = (unsigned short*)ws;  ws += (size_t)HID * FIN * 2; // B^T bf16 lo

    hipMemsetAsync(bucket_cnt, 0, 256 * 4, stream);

    bucket_kernel<<<NBKB, 256, 0, stream>>>(row, col, ew, bucket_cnt, staging);
    build_count_kernel<<<NB, 512, 0, stream>>>(staging, bucket_cnt,
                                               basev, endv, dis, ptot);
    bscan_w1cvt_kernel<<<5, 256, 0, stream>>>(ptot, bucket_base, W1, w1hi, w1lo);
    build_place_kernel<<<NB, 512, 0, stream>>>(staging, bucket_cnt, bucket_base,
                                               basev, endv, dis, eme);
    gemm1_mfma_kernel<<<(NN + 63) / 64, 256, 0, stream>>>(x, w1hi, w1lo, xw);
    gather1_kernel<<<(NN + 3) / 4, 256, 0, stream>>>(basev, endv, (const ull*)eme,
                                                     (const unsigned*)xw, dis, b1, h);
    gemm2_kernel<<<(NN + 63) / 64, 256, 0, stream>>>(h, W2, hw2);
    gather2_kernel<<<(NN + 3) / 4, 256, 0, stream>>>(basev, endv, (const ull*)eme,
                                                     (const unsigned*)hw2, dis, b2, out);
}

// Round 9
// 357.519 us; speedup vs baseline: 1.0884x; 1.0884x over previous
//
#include <hip/hip_runtime.h>
#include <hip/hip_bf16.h>
#include <math.h>

#define NN 100000
#define EE 1600000
#define FIN 256
#define HID 64
#define NC 40
#define NB 196        // destination buckets of 512 nodes (196*512 = 100352)
#define BCAP 10240    // staging capacity per bucket (mean 8192, +22 sigma)
#define CHUNK 2048    // edges per bucket_kernel block
#define NBKB ((EE + CHUNK - 1) / CHUNK)   // 782

typedef unsigned long long ull;
typedef __attribute__((ext_vector_type(2))) unsigned long long ullx2;
typedef __attribute__((ext_vector_type(8))) short short8;
typedef __attribute__((ext_vector_type(4))) float f32x4;

__device__ __forceinline__ unsigned short f2bf_rne(float f) {
    unsigned u = __float_as_uint(f);
    u += 0x7FFFu + ((u >> 16) & 1u);
    return (unsigned short)(u >> 16);
}
__device__ __forceinline__ float bf2f(unsigned short b) {
    return __uint_as_float((unsigned)b << 16);
}

// accumulate one edge: q = (w<<32)|src ; tbl rows are 32 dwords (64 bf16)
__device__ __forceinline__ void edge_acc(ull q, const unsigned* __restrict__ tbl,
                                         int fl, float& a0, float& a1) {
    unsigned src = (unsigned)q & 0x1FFFFu;
    unsigned u = tbl[(src << 5) | fl];
    float w = __int_as_float((int)(q >> 32));
    a0 += w * __uint_as_float(u << 16);
    a1 += w * __uint_as_float(u & 0xFFFF0000u);
}

// ---- stage edges into destination buckets; LDS-reorder by bucket for coalesced writes ----
__global__ __launch_bounds__(256) void bucket_kernel(const int* __restrict__ row,
                                                     const int* __restrict__ col,
                                                     const float* __restrict__ w,
                                                     int* __restrict__ bucket_cnt,
                                                     int2* __restrict__ staging) {
    __shared__ int2 spay[CHUNK];            // 16 KB  original-order payload
    __shared__ int2 sorted[CHUNK];          // 16 KB  bucket-ordered payload
    __shared__ unsigned char sb[CHUNK];     // 2 KB   bucket id per original slot
    __shared__ unsigned char sbk[CHUNK];    // 2 KB   bucket id per sorted slot
    __shared__ int lcnt[NB], lofs[NB], lstart[NB];
    __shared__ int sscan[256];
    const int tid = threadIdx.x;
    const int e0 = blockIdx.x * CHUNK;
    const int nE = min(CHUNK, EE - e0);
    for (int i = tid; i < nE; i += 256) {
        int e = e0 + i;
        int c = col[e];
        sb[i] = (unsigned char)(c >> 9);
        spay[i] = make_int2(((c & 511) << 17) | row[e], __float_as_int(w[e]));
    }
    for (int i = tid; i < NB; i += 256) lcnt[i] = 0;
    __syncthreads();
    for (int i = tid; i < nE; i += 256) atomicAdd(&lcnt[sb[i]], 1);
    __syncthreads();
    // exclusive scan of lcnt over NB (<=256)
    int v = (tid < NB) ? lcnt[tid] : 0;
    sscan[tid] = v;
    __syncthreads();
    for (int off = 1; off < 256; off <<= 1) {
        int u = (tid >= off) ? sscan[tid - off] : 0;
        __syncthreads();
        sscan[tid] += u;
        __syncthreads();
    }
    if (tid < NB) {
        lofs[tid] = sscan[tid] - v;                       // local exclusive prefix
        lstart[tid] = v ? atomicAdd(&bucket_cnt[tid], v) : 0;  // global base for this block's run
        lcnt[tid] = 0;
    }
    __syncthreads();
    // reorder into bucket-contiguous LDS
    for (int i = tid; i < nE; i += 256) {
        int b = sb[i];
        int p = lofs[b] + atomicAdd(&lcnt[b], 1);
        sorted[p] = spay[i];
        sbk[p] = (unsigned char)b;
    }
    __syncthreads();
    // write out: consecutive threads -> consecutive slots of the same bucket
    for (int p = tid; p < nE; p += 256) {
        int b = sbk[p];
        int slot = lstart[b] + (p - lofs[b]);
        if (slot < BCAP) staging[(size_t)b * BCAP + slot] = sorted[p];
    }
}

// ---- build pass A: per-dest count+degree; within-bucket scan of PADDED degrees ----
// basev <- within-bucket padded offset (fixed up in pass B); endv <- actual count
__global__ __launch_bounds__(512) void build_count_kernel(const int2* __restrict__ staging,
                                                          const int* __restrict__ bucket_cnt,
                                                          int* __restrict__ basev,
                                                          int* __restrict__ endv,
                                                          float* __restrict__ dis,
                                                          int* __restrict__ ptot) {
    __shared__ int dcnt[512];
    __shared__ float dsum[512];
    __shared__ int sscan[512];
    const int t = threadIdx.x;
    const int b = blockIdx.x;
    const int nE = min(bucket_cnt[b], BCAP);
    const int2* st = staging + (size_t)b * BCAP;
    dcnt[t] = 0; dsum[t] = 0.f;
    __syncthreads();
    for (int i = t; i < nE; i += 512) {
        int2 p = st[i];
        int d = p.x >> 17;
        atomicAdd(&dcnt[d], 1);
        atomicAdd(&dsum[d], __int_as_float(p.y));
    }
    __syncthreads();
    int c = dcnt[t];
    int pdeg = (c + 7) & ~7;       // pad each node's range to multiple of 8
    sscan[t] = pdeg;
    __syncthreads();
    for (int off = 1; off < 512; off <<= 1) {
        int u = (t >= off) ? sscan[t - off] : 0;
        __syncthreads();
        sscan[t] += u;
        __syncthreads();
    }
    int gd = b * 512 + t;
    if (gd < NN) {
        basev[gd] = sscan[t] - pdeg;   // within-bucket padded exclusive prefix
        endv[gd] = c;                  // actual count (temporarily)
        dis[gd] = rsqrtf(dsum[t] + 1.0f);   // self-loop weight 1
    }
    if (t == 511) ptot[b] = sscan[511];    // bucket padded total
}

// ---- block 0: exclusive scan of bucket padded totals; blocks 1..4: W1 -> B^T bf16 hi/lo ----
__global__ __launch_bounds__(256) void bscan_w1cvt_kernel(const int* __restrict__ ptot,
                                                          int* __restrict__ bucket_base,
                                                          const float* __restrict__ W1,
                                                          unsigned short* __restrict__ w1hi,
                                                          unsigned short* __restrict__ w1lo) {
    if (blockIdx.x == 0) {
        __shared__ int sd[256];
        int t = threadIdx.x;
        int v = (t < NB) ? ptot[t] : 0;
        sd[t] = v;
        __syncthreads();
        for (int off = 1; off < 256; off <<= 1) {
            int u = (t >= off) ? sd[t - off] : 0;
            __syncthreads();
            sd[t] += u;
            __syncthreads();
        }
        if (t < NB) bucket_base[t] = sd[t] - v;
    } else {
        int b = blockIdx.x - 1;          // 0..3
        for (int i = threadIdx.x; i < 4096; i += 256) {
            int e = b * 4096 + i;        // e = c*256 + k  (B^T layout)
            int c = e >> 8, k = e & 255;
            float v = W1[(size_t)k * HID + c];
            unsigned short h = f2bf_rne(v);
            w1hi[e] = h;
            w1lo[e] = f2bf_rne(v - bf2f(h));
        }
    }
}

// ---- build pass B: fix up global bases, place normalized edges, zero-fill pads ----
__global__ __launch_bounds__(512) void build_place_kernel(const int2* __restrict__ staging,
                                                          const int* __restrict__ bucket_cnt,
                                                          const int* __restrict__ bucket_base,
                                                          int* __restrict__ basev,
                                                          int* __restrict__ endv,
                                                          const float* __restrict__ dis,
                                                          int2* __restrict__ eme) {
    __shared__ int dcur[512];
    __shared__ float sdis[512];
    const int t = threadIdx.x;
    const int b = blockIdx.x;
    const int nE = min(bucket_cnt[b], BCAP);
    const int2* st = staging + (size_t)b * BCAP;
    const int gd = b * 512 + t;
    int gb = 0, c = 0, pdeg = 0;
    if (gd < NN) {
        gb = bucket_base[b] + basev[gd];
        c = endv[gd];
        pdeg = (c + 7) & ~7;
        basev[gd] = gb;
        endv[gd] = gb + c;
        sdis[t] = dis[gd];
    } else {
        sdis[t] = 0.f;
    }
    dcur[t] = gb;
    __syncthreads();
    for (int i = t; i < nE; i += 512) {
        int2 p = st[i];
        int d = p.x >> 17;
        int src = p.x & 0x1FFFF;
        int pos = atomicAdd(&dcur[d], 1);
        float wn = __int_as_float(p.y) * dis[src] * sdis[d];
        eme[pos] = make_int2(src, __float_as_int(wn));
    }
    // zero-weight pads: src=0 (valid row) x 0 weight
    for (int i = c; i < pdeg; i++) eme[gb + i] = make_int2(0, 0);
}

// ---- GEMM1 (MFMA, split-bf16 f32 emulation): xw[N,64](bf16) = x[N,256] @ W1[256,64] ----
// 512 threads = 8 waves, 16 rows/wave (128 rows/block, 782 blocks -> 6252 waves).
// B (W1 hi/lo) staged in LDS in two 4-ks phases (32 KB): the only per-wave VMEM is
// 16 independent A-loads; B comes from conflict-free ds_read_b128 shared by 8 waves.
__global__ __launch_bounds__(512, 4) void gemm1_mfma_kernel(const float* __restrict__ x,
                                                            const unsigned short* __restrict__ w1hi,
                                                            const unsigned short* __restrict__ w1lo,
                                                            __hip_bfloat16* __restrict__ xw) {
    __shared__ unsigned short shi[4096 * 2];   // [ (ksl*64+col)*32 + kk ] for 4 ks, 16 KB
    __shared__ unsigned short slo[4096 * 2];   // 16 KB
    const int tid = threadIdx.x;
    const int wid = tid >> 6;
    const int l   = tid & 63;
    const int r   = l & 15;        // A row within 16-tile / B col within 16-tile
    const int kg  = l >> 4;        // k-group 0..3 (8 contiguous k each)
    const int rb0 = blockIdx.x * 128 + wid * 16;   // wave's 16 rows

    f32x4 acc[4];
#pragma unroll
    for (int j = 0; j < 4; j++) acc[j] = (f32x4){0.f, 0.f, 0.f, 0.f};

    int row0 = rb0 + r;
    int row0c = row0 < NN ? row0 : NN - 1;   // clamp loads; stores are guarded
    const float* ap = x + (size_t)row0c * FIN + kg * 8;

#pragma unroll
    for (int ph = 0; ph < 2; ph++) {
        // stage 4 ks (K=128) of B^T hi+lo into LDS: 1024 16B-chunks per table
        for (int c2 = tid; c2 < 1024; c2 += 512) {
            int ckg = c2 & 3, ccol = (c2 >> 2) & 63, cksl = c2 >> 8;
            size_t src = (size_t)ccol * FIN + (ph * 4 + cksl) * 32 + ckg * 8;
            int dst = ((cksl * 64 + ccol) * 32 + ckg * 8);
            *(short8*)(shi + dst) = *(const short8*)(w1hi + src);
            *(short8*)(slo + dst) = *(const short8*)(w1lo + src);
        }
        __syncthreads();
#pragma unroll
        for (int ksl = 0; ksl < 4; ksl++) {
            const int ks = ph * 4 + ksl;
            // A: 8 contiguous f32 for this row-tile
            float4 afa = *(const float4*)(ap + ks * 32);
            float4 afb = *(const float4*)(ap + ks * 32 + 4);
            float av[8] = {afa.x, afa.y, afa.z, afa.w, afb.x, afb.y, afb.z, afb.w};
            short8 ahi, alo;
#pragma unroll
            for (int j = 0; j < 8; j++) {
                unsigned short hh = f2bf_rne(av[j]);
                ahi[j] = (short)hh;
                alo[j] = (short)f2bf_rne(av[j] - bf2f(hh));
            }
#pragma unroll
            for (int ct = 0; ct < 4; ct++) {
                int bo = ((ksl * 64 + ct * 16 + r) * 32 + kg * 8);
                short8 bh = *(const short8*)(shi + bo);
                short8 bl = *(const short8*)(slo + bo);
                acc[ct] = __builtin_amdgcn_mfma_f32_16x16x32_bf16(ahi, bh, acc[ct], 0, 0, 0);
                acc[ct] = __builtin_amdgcn_mfma_f32_16x16x32_bf16(ahi, bl, acc[ct], 0, 0, 0);
                acc[ct] = __builtin_amdgcn_mfma_f32_16x16x32_bf16(alo, bh, acc[ct], 0, 0, 0);
            }
        }
        __syncthreads();
    }
    // C/D layout: col = lane&15, row = (lane>>4)*4 + reg
#pragma unroll
    for (int i = 0; i < 4; i++) {
        int grow = rb0 + kg * 4 + i;
        if (grow < NN) {
            unsigned short* dst = (unsigned short*)xw + (size_t)grow * HID + r;
#pragma unroll
            for (int ct = 0; ct < 4; ct++)
                dst[ct * 16] = f2bf_rne(acc[ct][i]);
        }
    }
}

// ---- gather1: padded ranges -> zero predication, contiguous 16B loads ----
// Half h of the wave takes the h-th contiguous 8-edge sub-block of each 16-batch.
__global__ __launch_bounds__(256) void gather1_kernel(const int* __restrict__ basev,
                                                      const int* __restrict__ endv,
                                                      const ull* __restrict__ eme,
                                                      const unsigned* __restrict__ xw32,
                                                      const float* __restrict__ dis,
                                                      const float* __restrict__ b,
                                                      float* __restrict__ h) {
    int n = blockIdx.x * 4 + (threadIdx.x >> 6);
    if (n >= NN) return;
    int lane = threadIdx.x & 63;
    int half = lane >> 5;
    int fl = lane & 31;            // feature-pair index (features 2fl, 2fl+1)
    int s = basev[n], t = endv[n];
    int pdeg = (t - s + 7) & ~7;   // padded range length (pads are zero-weight)
    float acc0 = 0.f, acc1 = 0.f;
    int nb16 = pdeg >> 4;
    for (int bi = 0; bi < nb16; bi++) {
        const ull* pp = eme + s + bi * 16 + 8 * half;   // 16B-aligned by construction
        ullx2 qa = *(const ullx2*)(pp);
        ullx2 qb = *(const ullx2*)(pp + 2);
        ullx2 qc = *(const ullx2*)(pp + 4);
        ullx2 qd = *(const ullx2*)(pp + 6);
        edge_acc(qa[0], xw32, fl, acc0, acc1);
        edge_acc(qa[1], xw32, fl, acc0, acc1);
        edge_acc(qb[0], xw32, fl, acc0, acc1);
        edge_acc(qb[1], xw32, fl, acc0, acc1);
        edge_acc(qc[0], xw32, fl, acc0, acc1);
        edge_acc(qc[1], xw32, fl, acc0, acc1);
        edge_acc(qd[0], xw32, fl, acc0, acc1);
        edge_acc(qd[1], xw32, fl, acc0, acc1);
    }
    if (pdeg & 8) {                 // one 8-edge batch, 4 edges per half
        const ull* pp = eme + s + nb16 * 16 + 4 * half;
        ullx2 qa = *(const ullx2*)(pp);
        ullx2 qb = *(const ullx2*)(pp + 2);
        edge_acc(qa[0], xw32, fl, acc0, acc1);
        edge_acc(qa[1], xw32, fl, acc0, acc1);
        edge_acc(qb[0], xw32, fl, acc0, acc1);
        edge_acc(qb[1], xw32, fl, acc0, acc1);
    }
    acc0 += __shfl_xor(acc0, 32);
    acc1 += __shfl_xor(acc1, 32);
    float d = dis[n];
    unsigned un = xw32[((unsigned)n << 5) | fl];
    float2 bv = *(const float2*)(b + 2 * fl);
    float v0 = acc0 + d * d * __uint_as_float(un << 16) + bv.x;
    float v1 = acc1 + d * d * __uint_as_float(un & 0xFFFF0000u) + bv.y;
    if (lane < 32) {
        *(float2*)(h + (size_t)n * HID + 2 * fl) = make_float2(fmaxf(v0, 0.f), fmaxf(v1, 0.f));
    }
}

// ---- GEMM2: hw2[N,64-padded](bf16) = h[N,64] @ W2[64,40]; rows padded to one 128B line ----
__global__ __launch_bounds__(256) void gemm2_kernel(const float* __restrict__ h,
                                                    const float* __restrict__ W,
                                                    __hip_bfloat16* __restrict__ hw) {
    __shared__ float hs[64][65];
    __shared__ float Ws[HID * NC];
    const int tid = threadIdx.x;
    const int base = blockIdx.x * 64;
    for (int v = tid; v < 1024; v += 256) {
        int r = v >> 4, q = v & 15;
        int gr = base + r;
        float4 hv = make_float4(0.f, 0.f, 0.f, 0.f);
        if (gr < NN) hv = *(const float4*)(h + (size_t)gr * HID + q * 4);
        hs[r][q * 4 + 0] = hv.x; hs[r][q * 4 + 1] = hv.y;
        hs[r][q * 4 + 2] = hv.z; hs[r][q * 4 + 3] = hv.w;
    }
    for (int v = tid; v < HID * NC; v += 256) Ws[v] = W[v];
    __syncthreads();
    const int tx = tid & 7;
    const int ty = tid >> 3;
    float acc[2][5] = {};
#pragma unroll 8
    for (int k = 0; k < HID; k++) {
        float h0 = hs[ty * 2 + 0][k];
        float h1 = hs[ty * 2 + 1][k];
        const float* wr = &Ws[k * NC + tx * 5];
        float w0 = wr[0], w1 = wr[1], w2 = wr[2], w3 = wr[3], w4 = wr[4];
        acc[0][0] += h0 * w0; acc[0][1] += h0 * w1; acc[0][2] += h0 * w2;
        acc[0][3] += h0 * w3; acc[0][4] += h0 * w4;
        acc[1][0] += h1 * w0; acc[1][1] += h1 * w1; acc[1][2] += h1 * w2;
        acc[1][3] += h1 * w3; acc[1][4] += h1 * w4;
    }
#pragma unroll
    for (int i = 0; i < 2; i++) {
        int gr = base + ty * 2 + i;
        if (gr < NN) {
#pragma unroll
            for (int c = 0; c < 5; c++)
                hw[(size_t)gr * 64 + tx * 5 + c] = __float2bfloat16(acc[i][c]);
        }
    }
}

// ---- gather2 + final: padded ranges, zero predication; log_softmax fused ----
__global__ __launch_bounds__(256) void gather2_kernel(const int* __restrict__ basev,
                                                      const int* __restrict__ endv,
                                                      const ull* __restrict__ eme,
                                                      const unsigned* __restrict__ hw32,
                                                      const float* __restrict__ dis,
                                                      const float* __restrict__ b,
                                                      float* __restrict__ out) {
    int n = blockIdx.x * 4 + (threadIdx.x >> 6);
    if (n >= NN) return;
    int lane = threadIdx.x & 63;
    int half = lane >> 5;
    int fl = lane & 31;
    bool act = fl < 20;            // classes 2fl, 2fl+1 < 40
    int s = basev[n], t = endv[n];
    int pdeg = (t - s + 7) & ~7;
    float acc0 = 0.f, acc1 = 0.f;
    int nb16 = pdeg >> 4;
    for (int bi = 0; bi < nb16; bi++) {
        const ull* pp = eme + s + bi * 16 + 8 * half;
        ullx2 qa = *(const ullx2*)(pp);
        ullx2 qb = *(const ullx2*)(pp + 2);
        ullx2 qc = *(const ullx2*)(pp + 4);
        ullx2 qd = *(const ullx2*)(pp + 6);
        edge_acc(qa[0], hw32, fl, acc0, acc1);
        edge_acc(qa[1], hw32, fl, acc0, acc1);
        edge_acc(qb[0], hw32, fl, acc0, acc1);
        edge_acc(qb[1], hw32, fl, acc0, acc1);
        edge_acc(qc[0], hw32, fl, acc0, acc1);
        edge_acc(qc[1], hw32, fl, acc0, acc1);
        edge_acc(qd[0], hw32, fl, acc0, acc1);
        edge_acc(qd[1], hw32, fl, acc0, acc1);
    }
    if (pdeg & 8) {
        const ull* pp = eme + s + nb16 * 16 + 4 * half;
        ullx2 qa = *(const ullx2*)(pp);
        ullx2 qb = *(const ullx2*)(pp + 2);
        edge_acc(qa[0], hw32, fl, acc0, acc1);
        edge_acc(qa[1], hw32, fl, acc0, acc1);
        edge_acc(qb[0], hw32, fl, acc0, acc1);
        edge_acc(qb[1], hw32, fl, acc0, acc1);
    }
    acc0 += __shfl_xor(acc0, 32);
    acc1 += __shfl_xor(acc1, 32);
    float v0 = 0.f, v1 = 0.f, m = -INFINITY;
    if (act) {
        float d = dis[n];
        unsigned un = hw32[((unsigned)n << 5) | fl];
        float2 bv = *(const float2*)(b + 2 * fl);
        v0 = acc0 + d * d * __uint_as_float(un << 16) + bv.x;
        v1 = acc1 + d * d * __uint_as_float(un & 0xFFFF0000u) + bv.y;
        m = fmaxf(v0, v1);
    }
#pragma unroll
    for (int off = 16; off; off >>= 1) m = fmaxf(m, __shfl_xor(m, off));
    float e0 = act ? expf(v0 - m) : 0.f;
    float e1 = act ? expf(v1 - m) : 0.f;
    float sum = e0 + e1;
#pragma unroll
    for (int off = 16; off; off >>= 1) sum += __shfl_xor(sum, off);
    float lse = m + logf(sum);
    if (act && lane < 32) {
        size_t idx = (size_t)n * NC + 2 * fl;
        *(float2*)(out + idx) = make_float2(v0, v1);
        *(float2*)(out + (size_t)NN * NC + idx) = make_float2(v0 - lse, v1 - lse);
    }
}

extern "C" void kernel_launch(void* const* d_in, const int* in_sizes, int n_in,
                              void* d_out, int out_size, void* d_ws, size_t ws_size,
                              hipStream_t stream) {
    const float* x    = (const float*)d_in[0];
    const int*   eidx = (const int*)d_in[1];
    const float* ew   = (const float*)d_in[2];
    const float* W1   = (const float*)d_in[3];
    const float* b1   = (const float*)d_in[4];
    const float* W2   = (const float*)d_in[5];
    const float* b2   = (const float*)d_in[6];
    float* out = (float*)d_out;

    const int* row = eidx;
    const int* col = eidx + EE;

    char* ws = (char*)d_ws;
    int*   bucket_cnt  = (int*)ws;               ws += 256 * 4;
    int*   bucket_base = (int*)ws;               ws += 256 * 4;
    int*   ptot        = (int*)ws;               ws += 256 * 4;
    float* dis    = (float*)ws;                  ws += NN * 4;
    int*   basev  = (int*)ws;                    ws += NN * 4;
    int*   endv   = (int*)ws;                    ws += NN * 4;
    int2*  eme    = (int2*)ws;                   ws += ((size_t)EE + 8 * NN) * 8;  // padded
    __hip_bfloat16* xw = (__hip_bfloat16*)ws;    ws += (size_t)NN * HID * 2;
    // staging (16.06 MB) and h (25.6 MB) are never live simultaneously: union them
    char* unionp = ws;                           ws += (size_t)NN * HID * 4;
    int2*  staging = (int2*)unionp;              // NB*BCAP*8 = 16.06 MB <= 25.6 MB
    float* h       = (float*)unionp;
    __hip_bfloat16* hw2 = (__hip_bfloat16*)ws;   ws += (size_t)NN * 64 * 2;  // stride-64 padded
    unsigned short* w1hi = (unsigned short*)ws;  ws += (size_t)HID * FIN * 2; // B^T bf16 hi
    unsigned short* w1lo = (unsigned short*)ws;  ws += (size_t)HID * FIN * 2; // B^T bf16 lo

    hipMemsetAsync(bucket_cnt, 0, 256 * 4, stream);

    bucket_kernel<<<NBKB, 256, 0, stream>>>(row, col, ew, bucket_cnt, staging);
    build_count_kernel<<<NB, 512, 0, stream>>>(staging, bucket_cnt,
                                               basev, endv, dis, ptot);
    bscan_w1cvt_kernel<<<5, 256, 0, stream>>>(ptot, bucket_base, W1, w1hi, w1lo);
    build_place_kernel<<<NB, 512, 0, stream>>>(staging, bucket_cnt, bucket_base,
                                               basev, endv, dis, eme);
    gemm1_mfma_kernel<<<(NN + 127) / 128, 512, 0, stream>>>(x, w1hi, w1lo, xw);
    gather1_kernel<<<(NN + 3) / 4, 256, 0, stream>>>(basev, endv, (const ull*)eme,
                                                     (const unsigned*)xw, dis, b1, h);
    gemm2_kernel<<<(NN + 63) / 64, 256, 0, stream>>>(h, W2, hw2);
    gather2_kernel<<<(NN + 3) / 4, 256, 0, stream>>>(basev, endv, (const ull*)eme,
                                                     (const unsigned*)hw2, dis, b2, out);
}

// Round 10
// 350.245 us; speedup vs baseline: 1.1110x; 1.0208x over previous
//
#include <hip/hip_runtime.h>
#include <hip/hip_bf16.h>
#include <math.h>

#define NN 100000
#define EE 1600000
#define FIN 256
#define HID 64
#define NC 40
#define NB 196        // destination buckets of 512 nodes (196*512 = 100352)
#define BCAP 10240    // staging capacity per bucket (mean 8192, +22 sigma)
#define CHUNK 2048    // edges per bucket_kernel block
#define NBKB ((EE + CHUNK - 1) / CHUNK)   // 782
#define NGEMM ((NN + 127) / 128)          // 782 gemm blocks (128 rows each)

typedef unsigned long long ull;
typedef __attribute__((ext_vector_type(2))) unsigned long long ullx2;
typedef __attribute__((ext_vector_type(8))) short short8;
typedef __attribute__((ext_vector_type(4))) float f32x4;

__device__ __forceinline__ unsigned short f2bf_rne(float f) {
    unsigned u = __float_as_uint(f);
    u += 0x7FFFu + ((u >> 16) & 1u);
    return (unsigned short)(u >> 16);
}
__device__ __forceinline__ float bf2f(unsigned short b) {
    return __uint_as_float((unsigned)b << 16);
}

// accumulate one edge: q = (w<<32)|src ; tbl rows are 32 dwords (64 bf16)
__device__ __forceinline__ void edge_acc(ull q, const unsigned* __restrict__ tbl,
                                         int fl, float& a0, float& a1) {
    unsigned src = (unsigned)q & 0x1FFFFu;
    unsigned u = tbl[(src << 5) | fl];
    float w = __int_as_float((int)(q >> 32));
    a0 += w * __uint_as_float(u << 16);
    a1 += w * __uint_as_float(u & 0xFFFF0000u);
}

// ---- fused: blocks [0,NBKB) bucket-stage edges; blocks [NBKB,NBKB+NGEMM) gemm1 ----
// Both roles are latency-bound alone; co-residency overlaps them.
// LDS union: bucket needs 40240 B, gemm needs 32768 B -> 40960 static.
__global__ __launch_bounds__(512, 4) void fused_bucket_gemm1_kernel(
        const int* __restrict__ row, const int* __restrict__ col,
        const float* __restrict__ w, int* __restrict__ bucket_cnt,
        int2* __restrict__ staging,
        const float* __restrict__ x, const float* __restrict__ W1,
        __hip_bfloat16* __restrict__ xw) {
    __shared__ __align__(16) unsigned char smem[40960];
    const int tid = threadIdx.x;

    if (blockIdx.x < NBKB) {
        // ================= bucket role (512 threads) =================
        int2* spay   = (int2*)(smem);            // 16384
        int2* sorted = (int2*)(smem + 16384);    // 16384
        unsigned char* sb  = smem + 32768;       // 2048
        unsigned char* sbk = smem + 34816;       // 2048
        int* lcnt   = (int*)(smem + 36864);      // 784
        int* lofs   = (int*)(smem + 37648);      // 784
        int* lstart = (int*)(smem + 38432);      // 784
        int* sscan  = (int*)(smem + 39216);      // 1024
        const int e0 = blockIdx.x * CHUNK;
        const int nE = min(CHUNK, EE - e0);
        for (int i = tid; i < nE; i += 512) {
            int e = e0 + i;
            int c = col[e];
            sb[i] = (unsigned char)(c >> 9);
            spay[i] = make_int2(((c & 511) << 17) | row[e], __float_as_int(w[e]));
        }
        for (int i = tid; i < NB; i += 512) lcnt[i] = 0;
        __syncthreads();
        for (int i = tid; i < nE; i += 512) atomicAdd(&lcnt[sb[i]], 1);
        __syncthreads();
        // exclusive scan of lcnt over NB (<=256); threads >=256 just barrier
        int v = (tid < NB) ? lcnt[tid] : 0;
        if (tid < 256) sscan[tid] = v;
        __syncthreads();
        for (int off = 1; off < 256; off <<= 1) {
            int u = (tid >= off && tid < 256) ? sscan[tid - off] : 0;
            __syncthreads();
            if (tid < 256) sscan[tid] += u;
            __syncthreads();
        }
        if (tid < NB) {
            lofs[tid] = sscan[tid] - v;
            lstart[tid] = v ? atomicAdd(&bucket_cnt[tid], v) : 0;
            lcnt[tid] = 0;
        }
        __syncthreads();
        // reorder into bucket-contiguous LDS
        for (int i = tid; i < nE; i += 512) {
            int b = sb[i];
            int p = lofs[b] + atomicAdd(&lcnt[b], 1);
            sorted[p] = spay[i];
            sbk[p] = (unsigned char)b;
        }
        __syncthreads();
        // write out: consecutive threads -> consecutive slots of the same bucket
        for (int p = tid; p < nE; p += 512) {
            int b = sbk[p];
            int slot = lstart[b] + (p - lofs[b]);
            if (slot < BCAP) staging[(size_t)b * BCAP + slot] = sorted[p];
        }
    } else {
        // ================= gemm1 role (8 waves, 16 rows/wave) =================
        unsigned short* shi = (unsigned short*)(smem);           // 16384
        unsigned short* slo = (unsigned short*)(smem + 16384);   // 16384
        const int wid = tid >> 6;
        const int l   = tid & 63;
        const int r   = l & 15;
        const int kg  = l >> 4;
        const int rb0 = (blockIdx.x - NBKB) * 128 + wid * 16;

        f32x4 acc[4];
#pragma unroll
        for (int j = 0; j < 4; j++) acc[j] = (f32x4){0.f, 0.f, 0.f, 0.f};

        int row0 = rb0 + r;
        int row0c = row0 < NN ? row0 : NN - 1;
        const float* ap = x + (size_t)row0c * FIN + kg * 8;

#pragma unroll
        for (int ph = 0; ph < 2; ph++) {
            // stage+convert 4 ks of W1 (B^T hi/lo) into LDS
            for (int c2 = tid; c2 < 1024; c2 += 512) {
                int ckg = c2 & 3, ccol = (c2 >> 2) & 63, cksl = c2 >> 8;
                int kb = (ph * 4 + cksl) * 32 + ckg * 8;
                short8 vh, vl;
#pragma unroll
                for (int j = 0; j < 8; j++) {
                    float v = W1[(size_t)(kb + j) * HID + ccol];
                    unsigned short hh = f2bf_rne(v);
                    vh[j] = (short)hh;
                    vl[j] = (short)f2bf_rne(v - bf2f(hh));
                }
                int dst = (cksl * 64 + ccol) * 32 + ckg * 8;
                *(short8*)(shi + dst) = vh;
                *(short8*)(slo + dst) = vl;
            }
            __syncthreads();
#pragma unroll
            for (int ksl = 0; ksl < 4; ksl++) {
                const int ks = ph * 4 + ksl;
                float4 afa = *(const float4*)(ap + ks * 32);
                float4 afb = *(const float4*)(ap + ks * 32 + 4);
                float av[8] = {afa.x, afa.y, afa.z, afa.w, afb.x, afb.y, afb.z, afb.w};
                short8 ahi, alo;
#pragma unroll
                for (int j = 0; j < 8; j++) {
                    unsigned short hh = f2bf_rne(av[j]);
                    ahi[j] = (short)hh;
                    alo[j] = (short)f2bf_rne(av[j] - bf2f(hh));
                }
#pragma unroll
                for (int ct = 0; ct < 4; ct++) {
                    int bo = (ksl * 64 + ct * 16 + r) * 32 + kg * 8;
                    short8 bh = *(const short8*)(shi + bo);
                    short8 bl = *(const short8*)(slo + bo);
                    acc[ct] = __builtin_amdgcn_mfma_f32_16x16x32_bf16(ahi, bh, acc[ct], 0, 0, 0);
                    acc[ct] = __builtin_amdgcn_mfma_f32_16x16x32_bf16(ahi, bl, acc[ct], 0, 0, 0);
                    acc[ct] = __builtin_amdgcn_mfma_f32_16x16x32_bf16(alo, bh, acc[ct], 0, 0, 0);
                }
            }
            __syncthreads();
        }
        // C/D layout: col = lane&15, row = (lane>>4)*4 + reg
#pragma unroll
        for (int i = 0; i < 4; i++) {
            int grow = rb0 + kg * 4 + i;
            if (grow < NN) {
                unsigned short* dst = (unsigned short*)xw + (size_t)grow * HID + r;
#pragma unroll
                for (int ct = 0; ct < 4; ct++)
                    dst[ct * 16] = f2bf_rne(acc[ct][i]);
            }
        }
    }
}

// ---- build pass A: per-dest count+degree; padded scan; ATOMIC bucket-base reservation ----
// Writes FINAL basev/endv (global padded base + actual count) and dis.
__global__ __launch_bounds__(512) void build_count_kernel(const int2* __restrict__ staging,
                                                          const int* __restrict__ bucket_cnt,
                                                          int* __restrict__ basev,
                                                          int* __restrict__ endv,
                                                          float* __restrict__ dis,
                                                          int* __restrict__ gcnt) {
    __shared__ int dcnt[512];
    __shared__ float dsum[512];
    __shared__ int sscan[512];
    __shared__ int bbase;
    const int t = threadIdx.x;
    const int b = blockIdx.x;
    const int nE = min(bucket_cnt[b], BCAP);
    const int2* st = staging + (size_t)b * BCAP;
    dcnt[t] = 0; dsum[t] = 0.f;
    __syncthreads();
    for (int i = t; i < nE; i += 512) {
        int2 p = st[i];
        int d = p.x >> 17;
        atomicAdd(&dcnt[d], 1);
        atomicAdd(&dsum[d], __int_as_float(p.y));
    }
    __syncthreads();
    int c = dcnt[t];
    int pdeg = (c + 7) & ~7;       // pad each node's range to multiple of 8
    sscan[t] = pdeg;
    __syncthreads();
    for (int off = 1; off < 512; off <<= 1) {
        int u = (t >= off) ? sscan[t - off] : 0;
        __syncthreads();
        sscan[t] += u;
        __syncthreads();
    }
    if (t == 511) bbase = atomicAdd(gcnt, sscan[511]);   // bucket order in eme is irrelevant
    __syncthreads();
    int gb = bbase + sscan[t] - pdeg;
    int gd = b * 512 + t;
    if (gd < NN) {
        basev[gd] = gb;
        endv[gd] = gb + c;
        dis[gd] = rsqrtf(dsum[t] + 1.0f);   // self-loop weight 1
    }
}

// ---- build pass B: place normalized edges, zero-fill pads ----
__global__ __launch_bounds__(512) void build_place_kernel(const int2* __restrict__ staging,
                                                          const int* __restrict__ bucket_cnt,
                                                          const int* __restrict__ basev,
                                                          const int* __restrict__ endv,
                                                          const float* __restrict__ dis,
                                                          int2* __restrict__ eme) {
    __shared__ int dcur[512];
    __shared__ float sdis[512];
    const int t = threadIdx.x;
    const int b = blockIdx.x;
    const int nE = min(bucket_cnt[b], BCAP);
    const int2* st = staging + (size_t)b * BCAP;
    const int gd = b * 512 + t;
    int gb = 0, c = 0, pdeg = 0;
    if (gd < NN) {
        gb = basev[gd];
        c = endv[gd] - gb;
        pdeg = (c + 7) & ~7;
        sdis[t] = dis[gd];
    } else {
        sdis[t] = 0.f;
    }
    dcur[t] = gb;
    __syncthreads();
    for (int i = t; i < nE; i += 512) {
        int2 p = st[i];
        int d = p.x >> 17;
        int src = p.x & 0x1FFFF;
        int pos = atomicAdd(&dcur[d], 1);
        float wn = __int_as_float(p.y) * dis[src] * sdis[d];
        eme[pos] = make_int2(src, __float_as_int(wn));
    }
    // zero-weight pads: src=0 (valid row) x 0 weight
    for (int i = c; i < pdeg; i++) eme[gb + i] = make_int2(0, 0);
}

// ---- gather1: padded ranges -> zero predication, contiguous 16B loads ----
__global__ __launch_bounds__(256) void gather1_kernel(const int* __restrict__ basev,
                                                      const int* __restrict__ endv,
                                                      const ull* __restrict__ eme,
                                                      const unsigned* __restrict__ xw32,
                                                      const float* __restrict__ dis,
                                                      const float* __restrict__ b,
                                                      float* __restrict__ h) {
    int n = blockIdx.x * 4 + (threadIdx.x >> 6);
    if (n >= NN) return;
    int lane = threadIdx.x & 63;
    int half = lane >> 5;
    int fl = lane & 31;            // feature-pair index (features 2fl, 2fl+1)
    int s = basev[n], t = endv[n];
    int pdeg = (t - s + 7) & ~7;   // padded range length (pads are zero-weight)
    float acc0 = 0.f, acc1 = 0.f;
    int nb16 = pdeg >> 4;
    for (int bi = 0; bi < nb16; bi++) {
        const ull* pp = eme + s + bi * 16 + 8 * half;   // 16B-aligned by construction
        ullx2 qa = *(const ullx2*)(pp);
        ullx2 qb = *(const ullx2*)(pp + 2);
        ullx2 qc = *(const ullx2*)(pp + 4);
        ullx2 qd = *(const ullx2*)(pp + 6);
        edge_acc(qa[0], xw32, fl, acc0, acc1);
        edge_acc(qa[1], xw32, fl, acc0, acc1);
        edge_acc(qb[0], xw32, fl, acc0, acc1);
        edge_acc(qb[1], xw32, fl, acc0, acc1);
        edge_acc(qc[0], xw32, fl, acc0, acc1);
        edge_acc(qc[1], xw32, fl, acc0, acc1);
        edge_acc(qd[0], xw32, fl, acc0, acc1);
        edge_acc(qd[1], xw32, fl, acc0, acc1);
    }
    if (pdeg & 8) {                 // one 8-edge batch, 4 edges per half
        const ull* pp = eme + s + nb16 * 16 + 4 * half;
        ullx2 qa = *(const ullx2*)(pp);
        ullx2 qb = *(const ullx2*)(pp + 2);
        edge_acc(qa[0], xw32, fl, acc0, acc1);
        edge_acc(qa[1], xw32, fl, acc0, acc1);
        edge_acc(qb[0], xw32, fl, acc0, acc1);
        edge_acc(qb[1], xw32, fl, acc0, acc1);
    }
    acc0 += __shfl_xor(acc0, 32);
    acc1 += __shfl_xor(acc1, 32);
    float d = dis[n];
    unsigned un = xw32[((unsigned)n << 5) | fl];
    float2 bv = *(const float2*)(b + 2 * fl);
    float v0 = acc0 + d * d * __uint_as_float(un << 16) + bv.x;
    float v1 = acc1 + d * d * __uint_as_float(un & 0xFFFF0000u) + bv.y;
    if (lane < 32) {
        *(float2*)(h + (size_t)n * HID + 2 * fl) = make_float2(fmaxf(v0, 0.f), fmaxf(v1, 0.f));
    }
}

// ---- GEMM2: hw2[N,64-padded](bf16) = h[N,64] @ W2[64,40]; rows padded to one 128B line ----
__global__ __launch_bounds__(256) void gemm2_kernel(const float* __restrict__ h,
                                                    const float* __restrict__ W,
                                                    __hip_bfloat16* __restrict__ hw) {
    __shared__ float hs[64][65];
    __shared__ float Ws[HID * NC];
    const int tid = threadIdx.x;
    const int base = blockIdx.x * 64;
    for (int v = tid; v < 1024; v += 256) {
        int r = v >> 4, q = v & 15;
        int gr = base + r;
        float4 hv = make_float4(0.f, 0.f, 0.f, 0.f);
        if (gr < NN) hv = *(const float4*)(h + (size_t)gr * HID + q * 4);
        hs[r][q * 4 + 0] = hv.x; hs[r][q * 4 + 1] = hv.y;
        hs[r][q * 4 + 2] = hv.z; hs[r][q * 4 + 3] = hv.w;
    }
    for (int v = tid; v < HID * NC; v += 256) Ws[v] = W[v];
    __syncthreads();
    const int tx = tid & 7;
    const int ty = tid >> 3;
    float acc[2][5] = {};
#pragma unroll 8
    for (int k = 0; k < HID; k++) {
        float h0 = hs[ty * 2 + 0][k];
        float h1 = hs[ty * 2 + 1][k];
        const float* wr = &Ws[k * NC + tx * 5];
        float w0 = wr[0], w1 = wr[1], w2 = wr[2], w3 = wr[3], w4 = wr[4];
        acc[0][0] += h0 * w0; acc[0][1] += h0 * w1; acc[0][2] += h0 * w2;
        acc[0][3] += h0 * w3; acc[0][4] += h0 * w4;
        acc[1][0] += h1 * w0; acc[1][1] += h1 * w1; acc[1][2] += h1 * w2;
        acc[1][3] += h1 * w3; acc[1][4] += h1 * w4;
    }
#pragma unroll
    for (int i = 0; i < 2; i++) {
        int gr = base + ty * 2 + i;
        if (gr < NN) {
#pragma unroll
            for (int c = 0; c < 5; c++)
                hw[(size_t)gr * 64 + tx * 5 + c] = __float2bfloat16(acc[i][c]);
        }
    }
}

// ---- gather2 + final: padded ranges, zero predication; log_softmax fused ----
__global__ __launch_bounds__(256) void gather2_kernel(const int* __restrict__ basev,
                                                      const int* __restrict__ endv,
                                                      const ull* __restrict__ eme,
                                                      const unsigned* __restrict__ hw32,
                                                      const float* __restrict__ dis,
                                                      const float* __restrict__ b,
                                                      float* __restrict__ out) {
    int n = blockIdx.x * 4 + (threadIdx.x >> 6);
    if (n >= NN) return;
    int lane = threadIdx.x & 63;
    int half = lane >> 5;
    int fl = lane & 31;
    bool act = fl < 20;            // classes 2fl, 2fl+1 < 40
    int s = basev[n], t = endv[n];
    int pdeg = (t - s + 7) & ~7;
    float acc0 = 0.f, acc1 = 0.f;
    int nb16 = pdeg >> 4;
    for (int bi = 0; bi < nb16; bi++) {
        const ull* pp = eme + s + bi * 16 + 8 * half;
        ullx2 qa = *(const ullx2*)(pp);
        ullx2 qb = *(const ullx2*)(pp + 2);
        ullx2 qc = *(const ullx2*)(pp + 4);
        ullx2 qd = *(const ullx2*)(pp + 6);
        edge_acc(qa[0], hw32, fl, acc0, acc1);
        edge_acc(qa[1], hw32, fl, acc0, acc1);
        edge_acc(qb[0], hw32, fl, acc0, acc1);
        edge_acc(qb[1], hw32, fl, acc0, acc1);
        edge_acc(qc[0], hw32, fl, acc0, acc1);
        edge_acc(qc[1], hw32, fl, acc0, acc1);
        edge_acc(qd[0], hw32, fl, acc0, acc1);
        edge_acc(qd[1], hw32, fl, acc0, acc1);
    }
    if (pdeg & 8) {
        const ull* pp = eme + s + nb16 * 16 + 4 * half;
        ullx2 qa = *(const ullx2*)(pp);
        ullx2 qb = *(const ullx2*)(pp + 2);
        edge_acc(qa[0], hw32, fl, acc0, acc1);
        edge_acc(qa[1], hw32, fl, acc0, acc1);
        edge_acc(qb[0], hw32, fl, acc0, acc1);
        edge_acc(qb[1], hw32, fl, acc0, acc1);
    }
    acc0 += __shfl_xor(acc0, 32);
    acc1 += __shfl_xor(acc1, 32);
    float v0 = 0.f, v1 = 0.f, m = -INFINITY;
    if (act) {
        float d = dis[n];
        unsigned un = hw32[((unsigned)n << 5) | fl];
        float2 bv = *(const float2*)(b + 2 * fl);
        v0 = acc0 + d * d * __uint_as_float(un << 16) + bv.x;
        v1 = acc1 + d * d * __uint_as_float(un & 0xFFFF0000u) + bv.y;
        m = fmaxf(v0, v1);
    }
#pragma unroll
    for (int off = 16; off; off >>= 1) m = fmaxf(m, __shfl_xor(m, off));
    float e0 = act ? expf(v0 - m) : 0.f;
    float e1 = act ? expf(v1 - m) : 0.f;
    float sum = e0 + e1;
#pragma unroll
    for (int off = 16; off; off >>= 1) sum += __shfl_xor(sum, off);
    float lse = m + logf(sum);
    if (act && lane < 32) {
        size_t idx = (size_t)n * NC + 2 * fl;
        *(float2*)(out + idx) = make_float2(v0, v1);
        *(float2*)(out + (size_t)NN * NC + idx) = make_float2(v0 - lse, v1 - lse);
    }
}

extern "C" void kernel_launch(void* const* d_in, const int* in_sizes, int n_in,
                              void* d_out, int out_size, void* d_ws, size_t ws_size,
                              hipStream_t stream) {
    const float* x    = (const float*)d_in[0];
    const int*   eidx = (const int*)d_in[1];
    const float* ew   = (const float*)d_in[2];
    const float* W1   = (const float*)d_in[3];
    const float* b1   = (const float*)d_in[4];
    const float* W2   = (const float*)d_in[5];
    const float* b2   = (const float*)d_in[6];
    float* out = (float*)d_out;

    const int* row = eidx;
    const int* col = eidx + EE;

    char* ws = (char*)d_ws;
    int*   bucket_cnt  = (int*)ws;               ws += 256 * 4;
    int*   gcnt        = (int*)ws;               ws += 64 * 4;   // global padded-edge counter
    float* dis    = (float*)ws;                  ws += NN * 4;
    int*   basev  = (int*)ws;                    ws += NN * 4;
    int*   endv   = (int*)ws;                    ws += NN * 4;
    int2*  eme    = (int2*)ws;                   ws += ((size_t)EE + 8 * NN) * 8;  // padded
    __hip_bfloat16* xw = (__hip_bfloat16*)ws;    ws += (size_t)NN * HID * 2;
    // staging (16.06 MB) and h (25.6 MB) are never live simultaneously: union them
    char* unionp = ws;                           ws += (size_t)NN * HID * 4;
    int2*  staging = (int2*)unionp;              // NB*BCAP*8 = 16.06 MB <= 25.6 MB
    float* h       = (float*)unionp;
    __hip_bfloat16* hw2 = (__hip_bfloat16*)ws;   ws += (size_t)NN * 64 * 2;  // stride-64 padded

    // memset covers bucket_cnt (1 KB) + gcnt (contiguous)
    hipMemsetAsync(bucket_cnt, 0, 256 * 4 + 64 * 4, stream);

    fused_bucket_gemm1_kernel<<<NBKB + NGEMM, 512, 0, stream>>>(
        row, col, ew, bucket_cnt, staging, x, W1, xw);
    build_count_kernel<<<NB, 512, 0, stream>>>(staging, bucket_cnt,
                                               basev, endv, dis, gcnt);
    build_place_kernel<<<NB, 512, 0, stream>>>(staging, bucket_cnt,
                                               basev, endv, dis, eme);
    gather1_kernel<<<(NN + 3) / 4, 256, 0, stream>>>(basev, endv, (const ull*)eme,
                                                     (const unsigned*)xw, dis, b1, h);
    gemm2_kernel<<<(NN + 63) / 64, 256, 0, stream>>>(h, W2, hw2);
    gather2_kernel<<<(NN + 3) / 4, 256, 0, stream>>>(basev, endv, (const ull*)eme,
                                                     (const unsigned*)hw2, dis, b2, out);
}